// Round 3
// baseline (27.518 us; speedup 1.0000x reference)
//
#include <hip/hip_runtime.h>

#define NP 2990
#define NT 32
#define NC 21
#define NBLK 20   // 12 prior-blocks + 8 truth-blocks

// Segment boundaries: cumsum of SIZES[i]*BOXES[i] = 2166, 2766, 2916, 2970, 2986, 2990
__device__ __forceinline__ int segment_of(int p) {
    if (p < 2166) return 0;
    if (p < 2766) return 1;
    if (p < 2916) return 2;
    if (p < 2970) return 3;
    if (p < 2986) return 4;
    return 5;
}

// ws header (first 128 bytes, zeroed by hipMemsetAsync each launch)
struct WsHdr {
    unsigned done;     // arrival counter
    int base[24];      // baseline counts (no-scatter)
};
// ws body at offset 128
struct WsBody {
    float ov[NP];      // best_truth_ov per prior (pre-scatter)
    int   bti[NP];     // best_truth_idx per prior (pre-scatter)
    int   pred[NP];    // 21-class argmax per prior
    int   bpi[NT];     // best_prior_idx per truth
};

__global__ __launch_bounds__(256) void ssd_fused(
    const float* __restrict__ conf,     // conf_data[0] : [NP][NC]
    const float* __restrict__ priors,   // [NP][4] (cx,cy,w,h)
    const float* __restrict__ targets,  // targets[0] : [NT][5]
    WsHdr* __restrict__ hdr,
    WsBody* __restrict__ body,
    float* __restrict__ out)            // [6][4]
{
    __shared__ float s_tr[NT * 5];
    __shared__ int   s_cnt[24];
    __shared__ int   s_corr[24];
    __shared__ int   s_bpi[NT];
    __shared__ float s_lab[NT];
    __shared__ bool  s_last;

    const int tid = threadIdx.x;
    const int b   = blockIdx.x;

    if (b < 12) {
        // ---- per-prior: best-truth argmax, pred argmax, baseline counts ----
        if (tid < NT * 5) s_tr[tid] = targets[tid];
        if (tid < 24)     s_cnt[tid] = 0;
        __syncthreads();

        const int p = b * 256 + tid;
        if (p < NP) {
            float4 pr = reinterpret_cast<const float4*>(priors)[p];
            float px1 = pr.x - pr.z * 0.5f;
            float py1 = pr.y - pr.w * 0.5f;
            float px2 = pr.x + pr.z * 0.5f;
            float py2 = pr.y + pr.w * 0.5f;
            float ab  = (px2 - px1) * (py2 - py1);

            float best = -1.0f; int bi = 0;
            #pragma unroll 4
            for (int t = 0; t < NT; ++t) {
                float tx1 = s_tr[t*5+0], ty1 = s_tr[t*5+1];
                float tx2 = s_tr[t*5+2], ty2 = s_tr[t*5+3];
                float ix = fmaxf(fminf(tx2, px2) - fmaxf(tx1, px1), 0.0f);
                float iy = fmaxf(fminf(ty2, py2) - fmaxf(ty1, py1), 0.0f);
                float inter = ix * iy;
                float aa = (tx2 - tx1) * (ty2 - ty1);
                float ov = inter / (aa + ab - inter);
                if (ov > best) { best = ov; bi = t; }   // strict > keeps first max
            }
            body->ov[p]  = best;
            body->bti[p] = bi;

            const float* cp = conf + p * NC;
            float bc = cp[0]; int pred = 0;
            #pragma unroll
            for (int c = 1; c < NC; ++c) {
                float v = cp[c];
                if (v > bc) { bc = v; pred = c; }       // strict > keeps first max
            }
            body->pred[p] = pred;

            int ct = (best < 0.5f) ? 0 : ((int)s_tr[bi*5+4] + 1);
            int seg = segment_of(p);
            bool eq = (ct == pred);
            atomicAdd(&s_cnt[seg * 4 + (eq ? 0 : 1)], 1);
            if (ct > 0) atomicAdd(&s_cnt[seg * 4 + (eq ? 2 : 3)], 1);
        }
        __syncthreads();
        if (tid < 24 && s_cnt[tid] != 0) atomicAdd(&hdr->base[tid], s_cnt[tid]);
    } else {
        // ---- per-truth: best-prior argmax (one wave per truth) ----
        const int wave = tid >> 6;
        const int lane = tid & 63;
        const int t = (b - 12) * 4 + wave;

        const float tx1 = targets[t*5+0], ty1 = targets[t*5+1];
        const float tx2 = targets[t*5+2], ty2 = targets[t*5+3];
        const float aa  = (tx2 - tx1) * (ty2 - ty1);

        float best = -1.0f; int bi = NP;
        for (int p = lane; p < NP; p += 64) {
            float4 pr = reinterpret_cast<const float4*>(priors)[p];
            float px1 = pr.x - pr.z * 0.5f;
            float py1 = pr.y - pr.w * 0.5f;
            float px2 = pr.x + pr.z * 0.5f;
            float py2 = pr.y + pr.w * 0.5f;
            float ab  = (px2 - px1) * (py2 - py1);

            float ix = fmaxf(fminf(tx2, px2) - fmaxf(tx1, px1), 0.0f);
            float iy = fmaxf(fminf(ty2, py2) - fmaxf(ty1, py1), 0.0f);
            float inter = ix * iy;
            float ov = inter / (aa + ab - inter);
            if (ov > best) { best = ov; bi = p; }       // lane-local first max
        }
        #pragma unroll
        for (int off = 32; off > 0; off >>= 1) {
            float o = __shfl_xor(best, off);
            int   j = __shfl_xor(bi,   off);
            if (o > best || (o == best && j < bi)) { best = o; bi = j; }
        }
        if (lane == 0) body->bpi[t] = bi;
    }

    // ---- arrival: release writes, count arrivals; last block finalizes ----
    __threadfence();                 // release this thread's global writes
    __syncthreads();                 // all threads' fences done before arrival
    if (tid == 0) {
        unsigned old = atomicAdd(&hdr->done, 1u);
        s_last = (old == NBLK - 1);
    }
    __syncthreads();
    if (!s_last) return;
    __threadfence();                 // acquire: see all producers' writes

    // ---- finalize: last-wins scatter correction on <=32 priors ----
    if (tid < 24) s_corr[tid] = 0;
    if (tid < NT) { s_bpi[tid] = body->bpi[tid]; s_lab[tid] = targets[tid*5+4]; }
    __syncthreads();

    if (tid < NT) {
        const int t = tid;
        const int p = s_bpi[t];
        bool winner = true;                       // last-wins dedup
        for (int u = t + 1; u < NT; ++u)
            if (s_bpi[u] == p) { winner = false; break; }
        if (winner) {
            int   pred   = body->pred[p];
            float ov_old = body->ov[p];
            int   bt_old = body->bti[p];
            int ct_old = (ov_old < 0.5f) ? 0 : ((int)s_lab[bt_old] + 1);
            int ct_new = (int)s_lab[t] + 1;       // ov forced to 2.0 >= 0.5; always > 0
            int seg = segment_of(p);
            bool eq_o = (ct_old == pred);
            bool eq_n = (ct_new == pred);
            atomicAdd(&s_corr[seg * 4 + (eq_o ? 0 : 1)], -1);
            atomicAdd(&s_corr[seg * 4 + (eq_n ? 0 : 1)],  1);
            if (ct_old > 0) atomicAdd(&s_corr[seg * 4 + (eq_o ? 2 : 3)], -1);
            atomicAdd(&s_corr[seg * 4 + (eq_n ? 2 : 3)],  1);
        }
    }
    __syncthreads();

    if (tid < 24) out[tid] = (float)(hdr->base[tid] + s_corr[tid]);
}

extern "C" void kernel_launch(void* const* d_in, const int* in_sizes, int n_in,
                              void* d_out, int out_size, void* d_ws, size_t ws_size,
                              hipStream_t stream) {
    // Inputs (setup_inputs order): 0=loc_data (unused), 1=conf_data, 2=priors, 3=targets
    const float* conf    = (const float*)d_in[1];  // only batch 0 is read
    const float* priors  = (const float*)d_in[2];
    const float* targets = (const float*)d_in[3];  // only batch 0 is read
    float* out = (float*)d_out;

    WsHdr*  hdr  = (WsHdr*)d_ws;
    WsBody* body = (WsBody*)((char*)d_ws + 128);

    // zero the arrival counter + baseline counts every launch (graph-safe)
    hipMemsetAsync(d_ws, 0, 128, stream);

    hipLaunchKernelGGL(ssd_fused, dim3(NBLK), dim3(256), 0, stream,
                       conf, priors, targets, hdr, body, out);
}